// Round 3
// baseline (473.826 us; speedup 1.0000x reference)
//
#include <hip/hip_runtime.h>
#include <hip/hip_cooperative_groups.h>
#include <math.h>

namespace cg = cooperative_groups;

// Problem constants (match reference)
#define NQ 16384
#define NK 7933
#define DI 1024
#define HD 512
#define RANK_TARGET (NQ - 4915)   // ascending 0-based rank of sort(A1)[-int(0.3*NQ)]

typedef __bf16 bf16x8 __attribute__((ext_vector_type(8)));
typedef float  f32x4  __attribute__((ext_vector_type(4)));

#define GLOAD_LDS16(g, l)                                                     \
  __builtin_amdgcn_global_load_lds(                                           \
      (const __attribute__((address_space(1))) void*)(g),                     \
      (__attribute__((address_space(3))) void*)(l), 16, 0, 0)

// ---------------------------------------------------------------------------
// Fused fp32 -> bf16 conversion for query, key, wq_w, wk_w (8 elems / iter).
// Block 0 additionally zeroes the small accumulator region (v, z, scf) so the
// later kernels never need a dedicated zeroing node.
// ---------------------------------------------------------------------------
__global__ void conv_all(const float* __restrict__ q, const float* __restrict__ k,
                         const float* __restrict__ wq, const float* __restrict__ wk,
                         __bf16* __restrict__ qbf, __bf16* __restrict__ kbf,
                         __bf16* __restrict__ wqbf, __bf16* __restrict__ wkbf,
                         unsigned* __restrict__ zero_region) {
  if (blockIdx.x == 0) {
    for (int j = threadIdx.x; j < 1088; j += 256) zero_region[j] = 0u;
  }
  const int NQ8 = NQ * DI / 8;   // 2097152
  const int NK8 = NK * DI / 8;   // 1015424
  const int W8  = HD * DI / 8;   // 65536
  const int total = NQ8 + NK8 + 2 * W8;
  int i = blockIdx.x * blockDim.x + threadIdx.x;
  int stride = gridDim.x * blockDim.x;
  for (; i < total; i += stride) {
    const float* s; __bf16* d; int j;
    if (i < NQ8)                 { s = q;  d = qbf;  j = i; }
    else if (i < NQ8 + NK8)      { s = k;  d = kbf;  j = i - NQ8; }
    else if (i < NQ8 + NK8 + W8) { s = wq; d = wqbf; j = i - NQ8 - NK8; }
    else                         { s = wk; d = wkbf; j = i - NQ8 - NK8 - W8; }
    float4 a = ((const float4*)s)[2 * j];
    float4 b = ((const float4*)s)[2 * j + 1];
    bf16x8 o;
    o[0] = (__bf16)a.x; o[1] = (__bf16)a.y; o[2] = (__bf16)a.z; o[3] = (__bf16)a.w;
    o[4] = (__bf16)b.x; o[5] = (__bf16)b.y; o[6] = (__bf16)b.z; o[7] = (__bf16)b.w;
    ((bf16x8*)d)[j] = o;
  }
}

// ---------------------------------------------------------------------------
// C[M,512] = tanh(A[M,1024] @ B[512,1024]^T + bias)   (bf16 in, f32 out)
// 128x128 tile, BK=64, global_load_lds width-16 staging, XOR-swizzled LDS:
// lane fetches global chunk (lane&7)^(lane>>3) of its row, so logical chunk c
// of row r lives at LDS r*64 + ((c ^ (r&7))<<3). Fragment reads then hit each
// 4-bank group exactly 8x per wave64 (the conflict-free floor).
// ---------------------------------------------------------------------------
__global__ __launch_bounds__(256, 3)
void gemm_bt_tanh(const __bf16* __restrict__ A, const __bf16* __restrict__ B,
                  const float* __restrict__ bias, float* __restrict__ C, int M) {
  constexpr int K = DI;
  constexpr int N = HD;
  __shared__ __align__(16) __bf16 sA[128 * 64];
  __shared__ __align__(16) __bf16 sB[128 * 64];

  const int tid  = threadIdx.x;
  const int lane = tid & 63;
  const int wave = tid >> 6;
  const int wr = wave >> 1, wc = wave & 1;
  const int m0 = blockIdx.x * 128, n0 = blockIdx.y * 128;

  // staging coords: each wave-call covers one 8x64 segment (1 KiB)
  const int srow = lane >> 3;                   // 0..7 row within segment
  const int scol = (((lane & 7) ^ srow)) << 3;  // swizzled col (bf16 units)

  const int lrow = lane & 15;
  const int chi  = lane >> 4;                   // 0..3 chunk offset from ks

  f32x4 acc[4][4] = {};

  for (int kk = 0; kk < K; kk += 64) {
    __syncthreads();
#pragma unroll
    for (int c = 0; c < 4; ++c) {
      int seg = wave * 4 + c;             // 0..15, wave-uniform
      int row = seg * 8 + srow;           // 0..127
      int ga = m0 + row; if (ga > M - 1) ga = M - 1;  // clamp tail (rows>=M unused)
      GLOAD_LDS16(A + (size_t)ga * K + kk + scol, &sA[seg * 512]);
      GLOAD_LDS16(B + (size_t)(n0 + row) * K + kk + scol, &sB[seg * 512]);
    }
    __syncthreads();
#pragma unroll
    for (int ks = 0; ks < 64; ks += 32) {
      const int cc = (ks >> 3) + chi;                  // logical 16B chunk
      const int sw = ((cc ^ (lrow & 7)) << 3);         // swizzled bf16 offset
      bf16x8 af[4], bfr[4];
#pragma unroll
      for (int mi = 0; mi < 4; ++mi)
        af[mi] = *(const bf16x8*)(&sA[(wr * 64 + mi * 16 + lrow) * 64 + sw]);
#pragma unroll
      for (int ni = 0; ni < 4; ++ni)
        bfr[ni] = *(const bf16x8*)(&sB[(wc * 64 + ni * 16 + lrow) * 64 + sw]);
#pragma unroll
      for (int mi = 0; mi < 4; ++mi)
#pragma unroll
        for (int ni = 0; ni < 4; ++ni)
          acc[mi][ni] = __builtin_amdgcn_mfma_f32_16x16x32_bf16(af[mi], bfr[ni], acc[mi][ni], 0, 0, 0);
    }
  }

  // C/D layout: row = (lane>>4)*4 + reg, col = lane&15  [learn_hip m89]
  const int rbase = m0 + wr * 64 + ((lane >> 4) << 2);
  const int cbase = n0 + wc * 64 + (lane & 15);
#pragma unroll
  for (int mi = 0; mi < 4; ++mi) {
#pragma unroll
    for (int r = 0; r < 4; ++r) {
      int grow = rbase + mi * 16 + r;
      if (grow < M) {
#pragma unroll
        for (int ni = 0; ni < 4; ++ni) {
          int gcol = cbase + ni * 16;
          C[(size_t)grow * N + gcol] = tanhf(acc[mi][ni][r] + bias[gcol]);
        }
      }
    }
  }
}

// ---------------------------------------------------------------------------
// v[512] = sum_k wa[k] * ktanh[k,:] / max(||ktanh[k,:]||, 1e-12)
// ---------------------------------------------------------------------------
__global__ __launch_bounds__(256)
void reduce_v(const float* __restrict__ kt, const float* __restrict__ wa,
              float* __restrict__ v, int M) {
  __shared__ float vpart[4][512];
  const int tid = threadIdx.x, lane = tid & 63, wave = tid >> 6;
  const int gw = blockIdx.x * 4 + wave;
  const int tw = gridDim.x * 4;
  float acc[8] = {0, 0, 0, 0, 0, 0, 0, 0};
  for (int r = gw; r < M; r += tw) {
    const float4* p = (const float4*)(kt + (size_t)r * HD + lane * 8);
    float4 x = p[0], y = p[1];
    float ss = x.x * x.x + x.y * x.y + x.z * x.z + x.w * x.w
             + y.x * y.x + y.y * y.y + y.z * y.z + y.w * y.w;
#pragma unroll
    for (int off = 32; off; off >>= 1) ss += __shfl_xor(ss, off);
    float s = wa[r] / fmaxf(sqrtf(ss), 1e-12f);
    acc[0] += s * x.x; acc[1] += s * x.y; acc[2] += s * x.z; acc[3] += s * x.w;
    acc[4] += s * y.x; acc[5] += s * y.y; acc[6] += s * y.z; acc[7] += s * y.w;
  }
#pragma unroll
  for (int j = 0; j < 8; ++j) vpart[wave][lane * 8 + j] = acc[j];
  __syncthreads();
  for (int c = tid; c < 512; c += 256)
    atomicAdd(&v[c], vpart[0][c] + vpart[1][c] + vpart[2][c] + vpart[3][c]);
}

// ---------------------------------------------------------------------------
// Cooperative tail: A1 + exact order-stat + softmax + attn-weighted sum + y.
// ---------------------------------------------------------------------------
__device__ __forceinline__ unsigned mapf(float f) {
  unsigned b = __float_as_uint(f);
  return (b & 0x80000000u) ? ~b : (b | 0x80000000u);
}

// block-0-only two-level select over a 65536-bin histogram: finds bin b with
// prefix(b) <= rank < prefix(b)+hist[b]; exactly one thread writes outputs.
__device__ void scan_select(const unsigned* __restrict__ hist, unsigned rank,
                            int* __restrict__ out_bin, unsigned* __restrict__ out_rem) {
  __shared__ unsigned wsum[4];
  __shared__ int s_chunk;
  __shared__ unsigned s_rem;
  const int t = threadIdx.x, lane = t & 63, wave = t >> 6;
  unsigned local = 0;
  const unsigned* p = hist + t * 256;
  for (int j = 0; j < 256; ++j) local += p[j];
  unsigned pre = local;
#pragma unroll
  for (int off = 1; off < 64; off <<= 1) {
    unsigned u = __shfl_up(pre, off);
    if (lane >= off) pre += u;
  }
  if (lane == 63) wsum[wave] = pre;
  __syncthreads();
  unsigned woff = 0;
  for (int w = 0; w < wave; ++w) woff += wsum[w];
  unsigned excl = woff + pre - local;
  if (local > 0 && rank >= excl && rank < excl + local) { s_chunk = t; s_rem = rank - excl; }
  __syncthreads();
  const int c = s_chunk;
  rank = s_rem;
  unsigned v2 = hist[c * 256 + t];
  pre = v2;
#pragma unroll
  for (int off = 1; off < 64; off <<= 1) {
    unsigned u = __shfl_up(pre, off);
    if (lane >= off) pre += u;
  }
  __syncthreads();           // everyone done reading wsum from level 1
  if (lane == 63) wsum[wave] = pre;
  __syncthreads();
  woff = 0;
  for (int w = 0; w < wave; ++w) woff += wsum[w];
  excl = woff + pre - v2;
  if (v2 > 0 && rank >= excl && rank < excl + v2) {
    *out_bin = c * 256 + t;
    *out_rem = rank - excl;
  }
}

__global__ __launch_bounds__(256)
void tail_kernel(const float* __restrict__ qt, float* __restrict__ A1,
                 const float* __restrict__ v, const float* __restrict__ wa_b,
                 float* __restrict__ scf, int* __restrict__ sci,
                 unsigned* __restrict__ hist1, unsigned* __restrict__ hist2,
                 float* __restrict__ out_y, float* __restrict__ out_attn,
                 float* __restrict__ z, const float* __restrict__ cls_w,
                 const float* __restrict__ cls_b) {
  cg::grid_group grid = cg::this_grid();
  const int tid = threadIdx.x, lane = tid & 63, wave = tid >> 6;
  const int gtid = blockIdx.x * 256 + tid;   // 0..65535

  // P0: zero both histograms
  hist1[gtid] = 0u;
  hist2[gtid] = 0u;
  grid.sync();

  // P1: A1[r] = dot(qt[r,:], v)/max(||qt[r,:]||,eps) + wa_b  +  hi-16 histogram
  {
    const float4* vp = (const float4*)(v + lane * 8);
    const float4 v0 = vp[0], v1 = vp[1];
    const float wab = wa_b[0];
    const int gw = gtid >> 6;              // 0..1023
    for (int r = gw; r < NQ; r += 1024) {
      const float4* p = (const float4*)(qt + (size_t)r * HD + lane * 8);
      float4 x = p[0], y = p[1];
      float dot = x.x * v0.x + x.y * v0.y + x.z * v0.z + x.w * v0.w
                + y.x * v1.x + y.y * v1.y + y.z * v1.z + y.w * v1.w;
      float ss  = x.x * x.x + x.y * x.y + x.z * x.z + x.w * x.w
                + y.x * y.x + y.y * y.y + y.z * y.z + y.w * y.w;
#pragma unroll
      for (int off = 32; off; off >>= 1) { dot += __shfl_xor(dot, off); ss += __shfl_xor(ss, off); }
      if (lane == 0) {
        float a1 = dot / fmaxf(sqrtf(ss), 1e-12f) + wab;
        A1[r] = a1;
        atomicAdd(&hist1[mapf(a1) >> 16], 1u);
      }
    }
  }
  grid.sync();

  // P2: select hi bin + residual rank
  if (blockIdx.x == 0) scan_select(hist1, (unsigned)RANK_TARGET, &sci[0], (unsigned*)&sci[1]);
  grid.sync();

  // P3: lo-16 histogram among elements matching the hi bin
  if (gtid < NQ) {
    unsigned key = mapf(A1[gtid]);
    if ((int)(key >> 16) == sci[0]) atomicAdd(&hist2[key & 0xFFFFu], 1u);
  }
  grid.sync();

  // P4: select lo bin -> exact threshold value
  if (blockIdx.x == 0) {
    scan_select(hist2, (unsigned)sci[1], &sci[2], (unsigned*)&sci[3]);
    __syncthreads();
    if (tid == 0) {
      unsigned key = (((unsigned)sci[0]) << 16) | (unsigned)sci[2];
      unsigned bits = (key & 0x80000000u) ? (key ^ 0x80000000u) : ~key;
      scf[0] = __uint_as_float(bits);
    }
  }
  grid.sync();

  // P5: Z' = sum exp(thr(A1) - thre)   (softmax shift-invariant; base = thre)
  {
    const float thre = scf[0];
    float s = 0.f;
    if (gtid < NQ) {
      float x = A1[gtid]; x = (x > thre) ? x : 0.f;
      s = expf(x - thre);
    }
#pragma unroll
    for (int off = 32; off; off >>= 1) s += __shfl_xor(s, off);
    if (lane == 0) atomicAdd(&scf[2], s);
  }
  grid.sync();

  // P6: attn[r] = exp(thr(A1[r]) - thre)/Z' ; z += attn[r] * qt[r,:]
  {
    __shared__ float vpart[4][512];
    const float thre = scf[0], invZ = 1.f / scf[2];
    float acc[8] = {0, 0, 0, 0, 0, 0, 0, 0};
    const int gw = gtid >> 6;
    for (int r = gw; r < NQ; r += 1024) {
      float x = A1[r]; x = (x > thre) ? x : 0.f;
      float a = expf(x - thre) * invZ;
      if (lane == 0) out_attn[r] = a;
      const float4* p = (const float4*)(qt + (size_t)r * HD + lane * 8);
      float4 u = p[0], w = p[1];
      acc[0] += a * u.x; acc[1] += a * u.y; acc[2] += a * u.z; acc[3] += a * u.w;
      acc[4] += a * w.x; acc[5] += a * w.y; acc[6] += a * w.z; acc[7] += a * w.w;
    }
#pragma unroll
    for (int j = 0; j < 8; ++j) vpart[wave][lane * 8 + j] = acc[j];
    __syncthreads();
    for (int c = tid; c < 512; c += 256)
      atomicAdd(&z[c], vpart[0][c] + vpart[1][c] + vpart[2][c] + vpart[3][c]);
  }
  grid.sync();

  // P7: y = z . cls_w + cls_b
  if (blockIdx.x == 0 && wave == 0) {
    const float4* zp = (const float4*)(z + lane * 8);
    const float4* wp = (const float4*)(cls_w + lane * 8);
    float4 a = zp[0], b = zp[1], c = wp[0], d = wp[1];
    float dot = a.x * c.x + a.y * c.y + a.z * c.z + a.w * c.w
              + b.x * d.x + b.y * d.y + b.z * d.z + b.w * d.w;
#pragma unroll
    for (int off = 32; off; off >>= 1) dot += __shfl_xor(dot, off);
    if (lane == 0) out_y[0] = dot + cls_b[0];
  }
}

// ---------------------------------------------------------------------------
// Workspace layout (bytes), 69,275,904 total:
//   hist1/hist2 overlay wqbf/wkbf (dead after gemm_q, zeroed inside coop P0);
//   qtanh overlays kbf+ktanh (dead after reduce_v).
// ---------------------------------------------------------------------------
#define OFF_H1   0u          // 256 KB (over wqbf)
#define OFF_H2   262144u     // 256 KB (over wqbf)
#define OFF_WQBF 0u
#define OFF_WKBF 1048576u
#define OFF_QBF  2097152u
#define OFF_A1   35651584u
#define OFF_V    35717120u
#define OFF_Z    35719168u
#define OFF_SC   35721216u
#define OFF_KBF  35721472u
#define OFF_KT   51968256u
#define OFF_QT   35721472u

extern "C" void kernel_launch(void* const* d_in, const int* in_sizes, int n_in,
                              void* d_out, int out_size, void* d_ws, size_t ws_size,
                              hipStream_t stream) {
  const float* query = (const float*)d_in[0];
  const float* key_x = (const float*)d_in[1];
  const float* wq_w  = (const float*)d_in[2];
  const float* wq_b  = (const float*)d_in[3];
  const float* wk_w  = (const float*)d_in[4];
  const float* wk_b  = (const float*)d_in[5];
  const float* wa_w  = (const float*)d_in[6];
  const float* wa_b  = (const float*)d_in[7];
  const float* cls_w = (const float*)d_in[8];
  const float* cls_b = (const float*)d_in[9];
  float* out = (float*)d_out;

  char* ws = (char*)d_ws;
  __bf16* wqbf = (__bf16*)(ws + OFF_WQBF);
  __bf16* wkbf = (__bf16*)(ws + OFF_WKBF);
  __bf16* qbf  = (__bf16*)(ws + OFF_QBF);
  float*  A1   = (float*)(ws + OFF_A1);
  float*  v    = (float*)(ws + OFF_V);
  float*  z    = (float*)(ws + OFF_Z);
  float*  scf  = (float*)(ws + OFF_SC);
  int*    sci  = (int*)(scf + 8);
  __bf16* kbf  = (__bf16*)(ws + OFF_KBF);
  float*  ktanh = (float*)(ws + OFF_KT);
  float*  qtanh = (float*)(ws + OFF_QT);
  unsigned* hist1 = (unsigned*)(ws + OFF_H1);
  unsigned* hist2 = (unsigned*)(ws + OFF_H2);
  float* out_attn = out + 1;

  // Node 1: convert inputs to bf16; block 0 zeroes v/z/scf (1088 u32)
  conv_all<<<4096, 256, 0, stream>>>(query, key_x, wq_w, wk_w,
                                     qbf, kbf, wqbf, wkbf, (unsigned*)v);

  // Node 2: ktanh = tanh(key @ wk^T + wk_b)
  gemm_bt_tanh<<<dim3(62, 4), 256, 0, stream>>>(kbf, wkbf, wk_b, ktanh, NK);

  // Node 3: v = sum_k wa[k] * l2norm(ktanh[k,:])
  reduce_v<<<128, 256, 0, stream>>>(ktanh, wa_w, v, NK);

  // Node 4: qtanh = tanh(query @ wq^T + wq_b)   (overwrites kbf/ktanh region)
  gemm_bt_tanh<<<dim3(128, 4), 256, 0, stream>>>(qbf, wqbf, wq_b, qtanh, NQ);

  // Node 5: cooperative tail (A1, exact quantile, softmax, z, y)
  void* args[] = {&qtanh, &A1, &v, (void*)&wa_b, &scf, &sci, &hist1, &hist2,
                  &out, &out_attn, &z, (void*)&cls_w, (void*)&cls_b};
  hipLaunchCooperativeKernel((void*)tail_kernel, dim3(256), dim3(256), args, 0, stream);
}

// Round 5
// 280.832 us; speedup vs baseline: 1.6872x; 1.6872x over previous
//
#include <hip/hip_runtime.h>
#include <math.h>

// Problem constants (match reference)
#define NQ 16384
#define NK 7933
#define DI 1024
#define HD 512
#define RANK_TARGET 11469   // NQ - int(0.3*NQ): 0-based ascending rank of thre

typedef __bf16 bf16x8 __attribute__((ext_vector_type(8)));
typedef float  f32x4  __attribute__((ext_vector_type(4)));

#define GLOAD_LDS16(g, l)                                                     \
  __builtin_amdgcn_global_load_lds(                                           \
      (const __attribute__((address_space(1))) void*)(g),                     \
      (__attribute__((address_space(3))) void*)(l), 16, 0, 0)

__device__ __forceinline__ unsigned mapf(float f) {
  unsigned b = __float_as_uint(f);
  return (b & 0x80000000u) ? ~b : (b | 0x80000000u);
}

// ---------------------------------------------------------------------------
// Node 1: fp32 -> bf16 for query, key, wq_w, wk_w. Block 0 zeroes v/z/scf.
// ---------------------------------------------------------------------------
__global__ void conv_all(const float* __restrict__ q, const float* __restrict__ k,
                         const float* __restrict__ wq, const float* __restrict__ wk,
                         __bf16* __restrict__ qbf, __bf16* __restrict__ kbf,
                         __bf16* __restrict__ wqbf, __bf16* __restrict__ wkbf,
                         unsigned* __restrict__ zero_region) {
  if (blockIdx.x == 0) {
    for (int j = threadIdx.x; j < 1088; j += 256) zero_region[j] = 0u;
  }
  const int NQ8 = NQ * DI / 8;
  const int NK8 = NK * DI / 8;
  const int W8  = HD * DI / 8;
  const int total = NQ8 + NK8 + 2 * W8;
  int i = blockIdx.x * blockDim.x + threadIdx.x;
  int stride = gridDim.x * blockDim.x;
  for (; i < total; i += stride) {
    const float* s; __bf16* d; int j;
    if (i < NQ8)                 { s = q;  d = qbf;  j = i; }
    else if (i < NQ8 + NK8)      { s = k;  d = kbf;  j = i - NQ8; }
    else if (i < NQ8 + NK8 + W8) { s = wq; d = wqbf; j = i - NQ8 - NK8; }
    else                         { s = wk; d = wkbf; j = i - NQ8 - NK8 - W8; }
    float4 a = ((const float4*)s)[2 * j];
    float4 b = ((const float4*)s)[2 * j + 1];
    bf16x8 o;
    o[0] = (__bf16)a.x; o[1] = (__bf16)a.y; o[2] = (__bf16)a.z; o[3] = (__bf16)a.w;
    o[4] = (__bf16)b.x; o[5] = (__bf16)b.y; o[6] = (__bf16)b.z; o[7] = (__bf16)b.w;
    ((bf16x8*)d)[j] = o;
  }
}

// ---------------------------------------------------------------------------
// Nodes 2 & 4: C[M,512] = tanh(A[M,1024] @ B[512,1024]^T + bias), bf16->f32.
// 128x128 tile, BK=64, global_load_lds width-16, XOR-swizzled LDS.
// FUSE_A1: epilogue also accumulates A1dot[r] += sum(tanh*v[col]) and
// A1ss[r] += sum(tanh^2) via 16-lane shuffle reduce + 2 atomics per row.
// ---------------------------------------------------------------------------
template <bool FUSE_A1>
__global__ __launch_bounds__(256, 3)
void gemm_bt_tanh(const __bf16* __restrict__ A, const __bf16* __restrict__ B,
                  const float* __restrict__ bias, float* __restrict__ C, int M,
                  const float* __restrict__ v, float* __restrict__ A1dot,
                  float* __restrict__ A1ss) {
  constexpr int K = DI;
  constexpr int N = HD;
  __shared__ __align__(16) __bf16 sA[128 * 64];
  __shared__ __align__(16) __bf16 sB[128 * 64];

  const int tid  = threadIdx.x;
  const int lane = tid & 63;
  const int wave = tid >> 6;
  const int wr = wave >> 1, wc = wave & 1;
  const int m0 = blockIdx.x * 128, n0 = blockIdx.y * 128;

  const int srow = lane >> 3;                   // 0..7 row within segment
  const int scol = (((lane & 7) ^ srow)) << 3;  // swizzled col (bf16 units)

  const int lrow = lane & 15;
  const int chi  = lane >> 4;                   // 0..3 chunk offset from ks

  f32x4 acc[4][4] = {};

  for (int kk = 0; kk < K; kk += 64) {
    __syncthreads();
#pragma unroll
    for (int c = 0; c < 4; ++c) {
      int seg = wave * 4 + c;             // 0..15, wave-uniform
      int row = seg * 8 + srow;           // 0..127
      int ga = m0 + row; if (ga > M - 1) ga = M - 1;  // clamp tail
      GLOAD_LDS16(A + (size_t)ga * K + kk + scol, &sA[seg * 512]);
      GLOAD_LDS16(B + (size_t)(n0 + row) * K + kk + scol, &sB[seg * 512]);
    }
    __syncthreads();
#pragma unroll
    for (int ks = 0; ks < 64; ks += 32) {
      const int cc = (ks >> 3) + chi;                  // logical 16B chunk
      const int sw = ((cc ^ (lrow & 7)) << 3);         // swizzled bf16 offset
      bf16x8 af[4], bfr[4];
#pragma unroll
      for (int mi = 0; mi < 4; ++mi)
        af[mi] = *(const bf16x8*)(&sA[(wr * 64 + mi * 16 + lrow) * 64 + sw]);
#pragma unroll
      for (int ni = 0; ni < 4; ++ni)
        bfr[ni] = *(const bf16x8*)(&sB[(wc * 64 + ni * 16 + lrow) * 64 + sw]);
#pragma unroll
      for (int mi = 0; mi < 4; ++mi)
#pragma unroll
        for (int ni = 0; ni < 4; ++ni)
          acc[mi][ni] = __builtin_amdgcn_mfma_f32_16x16x32_bf16(af[mi], bfr[ni], acc[mi][ni], 0, 0, 0);
    }
  }

  // C/D layout: row = (lane>>4)*4 + reg, col = lane&15  [learn_hip m89]
  const int rbase = m0 + wr * 64 + ((lane >> 4) << 2);
  const int cbase = n0 + wc * 64 + (lane & 15);
  float b4[4], v4[4];
#pragma unroll
  for (int ni = 0; ni < 4; ++ni) {
    b4[ni] = bias[cbase + ni * 16];
    if constexpr (FUSE_A1) v4[ni] = v[cbase + ni * 16];
  }
#pragma unroll
  for (int mi = 0; mi < 4; ++mi) {
#pragma unroll
    for (int r = 0; r < 4; ++r) {
      int grow = rbase + mi * 16 + r;
      if (grow < M) {
        float pd = 0.f, pss = 0.f;
#pragma unroll
        for (int ni = 0; ni < 4; ++ni) {
          float val = tanhf(acc[mi][ni][r] + b4[ni]);
          C[(size_t)grow * N + cbase + ni * 16] = val;
          if constexpr (FUSE_A1) { pd += val * v4[ni]; pss += val * val; }
        }
        if constexpr (FUSE_A1) {
#pragma unroll
          for (int off = 1; off < 16; off <<= 1) {
            pd += __shfl_xor(pd, off);
            pss += __shfl_xor(pss, off);
          }
          if ((lane & 15) == 0) {
            atomicAdd(&A1dot[grow], pd);
            atomicAdd(&A1ss[grow], pss);
          }
        }
      }
    }
  }
}

// ---------------------------------------------------------------------------
// Node 3: v[512] = sum_k wa[k]*ktanh[k,:]/max(||ktanh[k,:]||,1e-12).
// Also zeroes A1dot/A1ss/keyg scratch (192 KB as 24576 uint2 over 64 blocks).
// ---------------------------------------------------------------------------
__global__ __launch_bounds__(256)
void reduce_v_zero(const float* __restrict__ kt, const float* __restrict__ wa,
                   float* __restrict__ v, int M, uint2* __restrict__ zr) {
  {
    int g = blockIdx.x * 256 + threadIdx.x;           // 64 blocks -> 16384
    uint2 zz; zz.x = 0u; zz.y = 0u;
    zr[g] = zz;
    if (g < 24576 - 16384) zr[16384 + g] = zz;
  }
  __shared__ float vpart[4][512];
  const int tid = threadIdx.x, lane = tid & 63, wave = tid >> 6;
  const int gw = blockIdx.x * 4 + wave;
  const int tw = gridDim.x * 4;
  float acc[8] = {0, 0, 0, 0, 0, 0, 0, 0};
  for (int r = gw; r < M; r += tw) {
    const float4* p = (const float4*)(kt + (size_t)r * HD + lane * 8);
    float4 x = p[0], y = p[1];
    float ss = x.x * x.x + x.y * x.y + x.z * x.z + x.w * x.w
             + y.x * y.x + y.y * y.y + y.z * y.z + y.w * y.w;
#pragma unroll
    for (int off = 32; off; off >>= 1) ss += __shfl_xor(ss, off);
    float s = wa[r] / fmaxf(sqrtf(ss), 1e-12f);
    acc[0] += s * x.x; acc[1] += s * x.y; acc[2] += s * x.z; acc[3] += s * x.w;
    acc[4] += s * y.x; acc[5] += s * y.y; acc[6] += s * y.z; acc[7] += s * y.w;
  }
#pragma unroll
  for (int j = 0; j < 8; ++j) vpart[wave][lane * 8 + j] = acc[j];
  __syncthreads();
  for (int c = tid; c < 512; c += 256)
    atomicAdd(&v[c], vpart[0][c] + vpart[1][c] + vpart[2][c] + vpart[3][c]);
}

// ---------------------------------------------------------------------------
// Node 5: single block, 1024 threads. Finalize A1 from A1dot/A1ss, write keys,
// then exact rank-11469 select via 16 rounds of 2-bit greedy MSB binary search
// (count of keys < candidate; contention-free, no histograms).
// ---------------------------------------------------------------------------
__global__ __launch_bounds__(1024)
void select_kernel(const float* __restrict__ A1dot, const float* __restrict__ A1ss,
                   const float* __restrict__ wa_b, float* __restrict__ A1,
                   unsigned* __restrict__ keyg, float* __restrict__ scf) {
  __shared__ unsigned wred1[16], wred2[16], wred3[16];
  __shared__ unsigned s_res;
  const int t = threadIdx.x, lane = t & 63, wave = t >> 6;
  const float wab = wa_b[0];
  unsigned kloc[16];
#pragma unroll 4
  for (int j = 0; j < 16; ++j) {
    int i = j * 1024 + t;
    float d = A1dot[i], ss = A1ss[i];
    float a1 = d / fmaxf(sqrtf(ss), 1e-12f) + wab;
    A1[i] = a1;
    unsigned k = mapf(a1);
    kloc[j] = k;
    keyg[i] = k;
  }
  if (t == 0) s_res = 0u;
  __syncthreads();

  for (int b = 30; b >= 0; b -= 2) {
    const unsigned res = s_res;
    const unsigned t1 = res | (1u << b);
    const unsigned t2 = res | (2u << b);
    const unsigned t3 = res | (3u << b);
    unsigned c1 = 0, c2 = 0, c3 = 0;
#pragma unroll
    for (int j = 0; j < 16; ++j) {
      unsigned k = kloc[j];
      c1 += (k < t1); c2 += (k < t2); c3 += (k < t3);
    }
#pragma unroll
    for (int off = 32; off; off >>= 1) {
      c1 += __shfl_xor(c1, off);
      c2 += __shfl_xor(c2, off);
      c3 += __shfl_xor(c3, off);
    }
    if (lane == 0) { wred1[wave] = c1; wred2[wave] = c2; wred3[wave] = c3; }
    __syncthreads();
    if (t == 0) {
      unsigned C1 = 0, C2 = 0, C3 = 0;
      for (int w = 0; w < 16; ++w) { C1 += wred1[w]; C2 += wred2[w]; C3 += wred3[w]; }
      unsigned nr = res;
      if (C3 <= RANK_TARGET)      nr = t3;
      else if (C2 <= RANK_TARGET) nr = t2;
      else if (C1 <= RANK_TARGET) nr = t1;
      s_res = nr;
    }
    __syncthreads();
  }
  if (t == 0) {
    unsigned key = s_res;
    unsigned bits = (key & 0x80000000u) ? (key ^ 0x80000000u) : ~key;
    scf[0] = __uint_as_float(bits);
  }
}

// ---------------------------------------------------------------------------
// Node 6: e(r) = exp(thr(A1[r]) - thre) -> out_attn (unnormalized);
// z'[c] += e(r)*qt[r,c]; S += e(r) into scf[2].
// ---------------------------------------------------------------------------
__global__ __launch_bounds__(256)
void expz(const float* __restrict__ A1, const float* __restrict__ qt,
          float* __restrict__ scf, float* __restrict__ e_out,
          float* __restrict__ z) {
  __shared__ float vpart[4][512];
  __shared__ float esum[4];
  const int tid = threadIdx.x, lane = tid & 63, wave = tid >> 6;
  const float thre = scf[0];
  const int gw = blockIdx.x * 4 + wave;
  const int tw = gridDim.x * 4;
  float acc[8] = {0, 0, 0, 0, 0, 0, 0, 0};
  float es = 0.f;
  for (int r = gw; r < NQ; r += tw) {
    float x = A1[r]; x = (x > thre) ? x : 0.f;
    float e = expf(x - thre);
    if (lane == 0) e_out[r] = e;
    es += e;
    const float4* p = (const float4*)(qt + (size_t)r * HD + lane * 8);
    float4 u = p[0], w = p[1];
    acc[0] += e * u.x; acc[1] += e * u.y; acc[2] += e * u.z; acc[3] += e * u.w;
    acc[4] += e * w.x; acc[5] += e * w.y; acc[6] += e * w.z; acc[7] += e * w.w;
  }
  if (lane == 0) esum[wave] = es;   // es identical across lanes of the wave
#pragma unroll
  for (int j = 0; j < 8; ++j) vpart[wave][lane * 8 + j] = acc[j];
  __syncthreads();
  for (int c = tid; c < 512; c += 256)
    atomicAdd(&z[c], vpart[0][c] + vpart[1][c] + vpart[2][c] + vpart[3][c]);
  if (tid == 0) atomicAdd(&scf[2], esum[0] + esum[1] + esum[2] + esum[3]);
}

// ---------------------------------------------------------------------------
// Node 7: attn *= 1/S (blocks 0..63); block 64: y = (z'.cls_w)/S + cls_b.
// ---------------------------------------------------------------------------
__global__ __launch_bounds__(256)
void finalize(float* __restrict__ attn, const float* __restrict__ scf,
              const float* __restrict__ z, const float* __restrict__ cls_w,
              const float* __restrict__ cls_b, float* __restrict__ y) {
  const float invZ = 1.f / scf[2];
  if (blockIdx.x < 64) {
    int i = blockIdx.x * 256 + threadIdx.x;
    attn[i] *= invZ;
  } else if (threadIdx.x < 64) {
    const int lane = threadIdx.x;
    const float4* zp = (const float4*)(z + lane * 8);
    const float4* wp = (const float4*)(cls_w + lane * 8);
    float4 a = zp[0], b = zp[1], c = wp[0], d = wp[1];
    float dot = a.x * c.x + a.y * c.y + a.z * c.z + a.w * c.w
              + b.x * d.x + b.y * d.y + b.z * d.z + b.w * d.w;
#pragma unroll
    for (int off = 32; off; off >>= 1) dot += __shfl_xor(dot, off);
    if (lane == 0) y[0] = dot * invZ + cls_b[0];
  }
}

// ---------------------------------------------------------------------------
// Workspace layout (bytes), max end = 69,275,904:
//   A1dot/A1ss/keyg overlay wkbf tail region (dead after gemm_k; zeroed node 3)
//   qtanh overlays kbf+ktanh (dead after reduce_v)
// ---------------------------------------------------------------------------
#define OFF_WQBF 0u
#define OFF_WKBF 1048576u
#define OFF_A1D  1048576u      // 64 KB (over wkbf)
#define OFF_A1S  1114112u      // 64 KB
#define OFF_KEY  1179648u      // 64 KB
#define OFF_QBF  2097152u
#define OFF_A1   35651584u
#define OFF_V    35717120u
#define OFF_Z    35719168u
#define OFF_SC   35721216u
#define OFF_KBF  35721472u
#define OFF_KT   51968256u
#define OFF_QT   35721472u

extern "C" void kernel_launch(void* const* d_in, const int* in_sizes, int n_in,
                              void* d_out, int out_size, void* d_ws, size_t ws_size,
                              hipStream_t stream) {
  const float* query = (const float*)d_in[0];
  const float* key_x = (const float*)d_in[1];
  const float* wq_w  = (const float*)d_in[2];
  const float* wq_b  = (const float*)d_in[3];
  const float* wk_w  = (const float*)d_in[4];
  const float* wk_b  = (const float*)d_in[5];
  const float* wa_w  = (const float*)d_in[6];
  const float* wa_b  = (const float*)d_in[7];
  const float* cls_w = (const float*)d_in[8];
  const float* cls_b = (const float*)d_in[9];
  float* out = (float*)d_out;

  char* ws = (char*)d_ws;
  __bf16* wqbf  = (__bf16*)(ws + OFF_WQBF);
  __bf16* wkbf  = (__bf16*)(ws + OFF_WKBF);
  float*  A1dot = (float*)(ws + OFF_A1D);
  float*  A1ss  = (float*)(ws + OFF_A1S);
  unsigned* keyg = (unsigned*)(ws + OFF_KEY);
  __bf16* qbf   = (__bf16*)(ws + OFF_QBF);
  float*  A1    = (float*)(ws + OFF_A1);
  float*  v     = (float*)(ws + OFF_V);
  float*  z     = (float*)(ws + OFF_Z);
  float*  scf   = (float*)(ws + OFF_SC);
  __bf16* kbf   = (__bf16*)(ws + OFF_KBF);
  float*  ktanh = (float*)(ws + OFF_KT);
  float*  qtanh = (float*)(ws + OFF_QT);
  float*  out_attn = out + 1;

  // 1: convert to bf16 (+ zero v/z/scf)
  conv_all<<<4096, 256, 0, stream>>>(query, key_x, wq_w, wk_w,
                                     qbf, kbf, wqbf, wkbf, (unsigned*)v);

  // 2: ktanh = tanh(key @ wk^T + wk_b)
  gemm_bt_tanh<false><<<dim3(62, 4), 256, 0, stream>>>(
      kbf, wkbf, wk_b, ktanh, NK, nullptr, nullptr, nullptr);

  // 3: v = sum_k wa[k]*l2norm(ktanh[k,:])  (+ zero A1dot/A1ss/keyg)
  reduce_v_zero<<<64, 256, 0, stream>>>(ktanh, wa_w, v, NK, (uint2*)A1dot);

  // 4: qtanh = tanh(query @ wq^T + wq_b) with fused A1 partial dot/ss
  gemm_bt_tanh<true><<<dim3(128, 4), 256, 0, stream>>>(
      qbf, wqbf, wq_b, qtanh, NQ, v, A1dot, A1ss);

  // 5: finalize A1 + exact rank-11469 threshold (single block)
  select_kernel<<<1, 1024, 0, stream>>>(A1dot, A1ss, wa_b, A1, keyg, scf);

  // 6: e(r), z' accumulation, S
  expz<<<128, 256, 0, stream>>>(A1, qtanh, scf, out_attn, z);

  // 7: normalize attn; y
  finalize<<<65, 256, 0, stream>>>(out_attn, scf, z, cls_w, cls_b, out);
}